// Round 7
// baseline (36461.096 us; speedup 1.0000x reference)
//
#include <hip/hip_runtime.h>
#include <math.h>

#define T_STEPS 4096
#define RES     2048
#define NF      8
#define NR      8
#define K_WG    256      // WG k owns columns [8k, 8k+8), one per wave
#define REC_THR 512      // 8 waves
#define RO_THR  256
#define SENTINEL 2.0f    // reachable |x| < 1 strictly (|x|<=0.7|x|+0.3); 2.0 unreachable

// ---------------------------------------------------------------------------
// drive[t][j] = Win[0][j] + sum_f inp[t][f] * Win[1+f][j]
__global__ void k_drive(const float* __restrict__ inp, const float* __restrict__ Win,
                        float* __restrict__ drive) {
    int idx = blockIdx.x * blockDim.x + threadIdx.x;   // [0, T*RES)
    int t = idx >> 11;
    int j = idx & (RES - 1);
    float d = Win[j];
#pragma unroll
    for (int f = 0; f < NF; ++f)
        d += inp[t * NF + f] * Win[(1 + f) * RES + j];
    drive[idx] = d;
}

// ---------------------------------------------------------------------------
// X[0][:] = 0 (valid initial state); X[1..T][:] = SENTINEL (unwritten)
__global__ void k_init(float* __restrict__ X) {
    int tid = threadIdx.x + blockIdx.x * blockDim.x;
    int stride = blockDim.x * gridDim.x;
    const int total = (T_STEPS + 1) * RES;
    for (int i = tid; i < total; i += stride)
        X[i] = (i < RES) ? 0.f : SENTINEL;
}

// ---------------------------------------------------------------------------
// Persistent dataflow recurrence, round 7 (= round-6 design, compile fix:
// no vector-typed inline-asm operands — gfx950 backend rejects tied vector
// registers; scalar "+v" ties are fine).
//  - Wave w of WG k produces column c = 8k+w and polls row-chunk w
//    (columns [256w, 256w+256)) of row t.
//  - W fragment (32 floats/lane) loaded ONCE before the t-loop via asm
//    volatile global_load_dword — un-sinkable, closing the R1–R4 failure
//    mode (allocator re-streamed W every step; VGPR 84/112/76/60, FETCH
//    up to 1 GB).
//  - Per step: poll own chunk with 4 scalar agent-scope atomic loads
//    (sentinel-in-data), stage to LDS, publish monotone generation tag
//    (release). Consume the other 7 chunks by spinning on their tags
//    (same-address ds_read = broadcast) — no staging wave, no barrier.
//  - 2-buffer safety without clearing: a wave staging generation t+2 into
//    buffer (t&1) observed row t+2 complete globally, which requires every
//    wave's x_{t+1} store, which data-depends on having fully consumed
//    generation t from that same buffer.
__global__ __launch_bounds__(REC_THR, 2) void k_recur(
        const float* __restrict__ W, const float* __restrict__ drive,
        float* __restrict__ X) {
    __shared__ float    xl[2][RES];    // 16 KB staged row, double-buffered
    __shared__ unsigned tag[2][8];     // per-chunk generation: last staged t+1

    const int tid  = threadIdx.x;
    const int wave = tid >> 6;
    const int lane = tid & 63;
    const int c    = blockIdx.x * 8 + wave;   // produced column
    const int base = 4 * lane;                // offset within a 256-elem chunk

    // ---- one-time: W fragment via un-sinkable asm loads ------------------
    float4 Wr[8];
#pragma unroll
    for (int g = 0; g < 8; ++g) {
        float w0, w1, w2, w3;
        const float* p0 = &W[(size_t)(g * 256 + base + 0) * RES + c];
        const float* p1 = p0 + RES;
        const float* p2 = p1 + RES;
        const float* p3 = p2 + RES;
        asm volatile("global_load_dword %0, %1, off" : "=v"(w0) : "v"(p0));
        asm volatile("global_load_dword %0, %1, off" : "=v"(w1) : "v"(p1));
        asm volatile("global_load_dword %0, %1, off" : "=v"(w2) : "v"(p2));
        asm volatile("global_load_dword %0, %1, off" : "=v"(w3) : "v"(p3));
        asm volatile("s_waitcnt vmcnt(0)"
                     : "+v"(w0), "+v"(w1), "+v"(w2), "+v"(w3));
        Wr[g] = make_float4(w0, w1, w2, w3);
    }

    if (tid < 16) tag[tid >> 3][tid & 7] = 0u;
    __syncthreads();   // one-time init barrier

    float xprev = 0.f;   // lane 0: own column's x_t (x_0 = 0)

    for (int t = 0; t < T_STEPS; ++t) {
        // Independent of x_t: drive for this wave's column.
        float dr = (lane == 0) ? drive[(size_t)t * RES + c] : 0.f;

        // ---- poll own global chunk of row t (sentinel-in-data) ----------
        const float* pc = X + (size_t)t * RES + wave * 256 + base;
        float x0, x1, x2, x3;
        for (;;) {
            x0 = __hip_atomic_load(pc + 0, __ATOMIC_RELAXED, __HIP_MEMORY_SCOPE_AGENT);
            x1 = __hip_atomic_load(pc + 1, __ATOMIC_RELAXED, __HIP_MEMORY_SCOPE_AGENT);
            x2 = __hip_atomic_load(pc + 2, __ATOMIC_RELAXED, __HIP_MEMORY_SCOPE_AGENT);
            x3 = __hip_atomic_load(pc + 3, __ATOMIC_RELAXED, __HIP_MEMORY_SCOPE_AGENT);
            float m = fmaxf(fmaxf(__builtin_fabsf(x0), __builtin_fabsf(x1)),
                            fmaxf(__builtin_fabsf(x2), __builtin_fabsf(x3)));
            if (__all(m < 1.5f)) break;
            __builtin_amdgcn_s_sleep(1);
        }

        const int b = t & 1;
        // Stage chunk to LDS; release-store the tag (drains ds_writes first).
        *reinterpret_cast<float4*>(&xl[b][wave * 256 + base]) =
            make_float4(x0, x1, x2, x3);
        if (lane == 0)
            __hip_atomic_store(&tag[b][wave], (unsigned)(t + 1),
                               __ATOMIC_RELEASE, __HIP_MEMORY_SCOPE_WORKGROUP);

        // ---- dot product: own chunk from registers ----------------------
        float a = 0.f;
        a = fmaf(x0, Wr[wave].x, a);
        a = fmaf(x1, Wr[wave].y, a);
        a = fmaf(x2, Wr[wave].z, a);
        a = fmaf(x3, Wr[wave].w, a);

        // ---- other 7 chunks as their tags arrive (staggered start) ------
#pragma unroll
        for (int gg = 1; gg < 8; ++gg) {
            int g = (wave + gg) & 7;
            while (__hip_atomic_load(&tag[b][g], __ATOMIC_ACQUIRE,
                                     __HIP_MEMORY_SCOPE_WORKGROUP) < (unsigned)(t + 1))
                ;   // same-address LDS spin: broadcast, cheap
            float4 xq = *reinterpret_cast<const float4*>(&xl[b][g * 256 + base]);
            a = fmaf(xq.x, Wr[g].x, a);
            a = fmaf(xq.y, Wr[g].y, a);
            a = fmaf(xq.z, Wr[g].z, a);
            a = fmaf(xq.w, Wr[g].w, a);
        }

        // ---- 64-lane butterfly: lane 0 ends with the full column sum ----
#pragma unroll
        for (int off = 32; off >= 1; off >>= 1)
            a += __shfl_xor(a, off, 64);

        if (lane == 0) {
            float xn = 0.7f * xprev + 0.3f * tanhf(dr + a);
            xprev = xn;
            __hip_atomic_store(&X[(size_t)(t + 1) * RES + c], xn,
                               __ATOMIC_RELAXED, __HIP_MEMORY_SCOPE_AGENT);
        }
    }
}

// ---------------------------------------------------------------------------
// Y[t][r] = Wout[0][r] + sum_f inp[t][f]*Wout[1+f][r] + sum_j X[t+1][j]*Wout[9+j][r]
__global__ void k_readout(const float* __restrict__ inp, const float* __restrict__ Wout,
                          const float* __restrict__ X, float* __restrict__ Y) {
    int t   = blockIdx.x;
    int tid = threadIdx.x;
    int r   = tid & (NR - 1);
    int gph = tid >> 3;                    // 32 groups
    const float* x = X + (size_t)(t + 1) * RES;
    float p = 0.f;
#pragma unroll 4
    for (int m = 0; m < RES / 32; ++m) {
        int j = gph * (RES / 32) + m;
        p += x[j] * Wout[(size_t)(1 + NF + j) * NR + r];
    }
    __shared__ float red[RO_THR];
    red[tid] = p;
    __syncthreads();
    for (int s = RO_THR / 2; s >= NR; s >>= 1) {
        if (tid < s) red[tid] += red[tid + s];
        __syncthreads();
    }
    if (tid < NR) {
        float y = Wout[tid];
#pragma unroll
        for (int f = 0; f < NF; ++f)
            y += inp[t * NF + f] * Wout[(1 + f) * NR + tid];
        Y[t * NR + tid] = y + red[tid];
    }
}

// ---------------------------------------------------------------------------
extern "C" void kernel_launch(void* const* d_in, const int* in_sizes, int n_in,
                              void* d_out, int out_size, void* d_ws, size_t ws_size,
                              hipStream_t stream) {
    const float* inp  = (const float*)d_in[0];   // (T, 8)
    const float* Win  = (const float*)d_in[1];   // (9, 2048)
    const float* W    = (const float*)d_in[2];   // (2048, 2048)
    const float* Wout = (const float*)d_in[3];   // (2057, 8)
    float* Y = (float*)d_out;                    // (T, 8)

    float* drive = (float*)d_ws;                            // 32 MB
    float* X     = drive + (size_t)T_STEPS * RES;           // 32 MB + 8 KB

    k_init<<<2048, 256, 0, stream>>>(X);
    k_drive<<<(T_STEPS * RES) / 256, 256, 0, stream>>>(inp, Win, drive);
    k_recur<<<K_WG, REC_THR, 0, stream>>>(W, drive, X);
    k_readout<<<T_STEPS, RO_THR, 0, stream>>>(inp, Wout, X, Y);
}